// Round 3
// baseline (4013.754 us; speedup 1.0000x reference)
//
#include <hip/hip_runtime.h>

#define NTOT 4194304
#define EPS_ 1e-5f

// ---------------- weight transpose: dwT[l][(ci*9+kk)][co], owT[l][(ci*9+k)][o] ----------------
__global__ __launch_bounds__(256) void transpose_w(
    const float* __restrict__ dw, const float* __restrict__ ow,
    float* __restrict__ dwT, float* __restrict__ owT)
{
    int i = blockIdx.x*256 + threadIdx.x;
    const int N1 = 7*36864;
    if (i < N1) {
        int l = i / 36864, r = i - l*36864;
        int co = r & 63, ik = r >> 6;
        int ci = ik / 9, kk = ik - ci*9;
        dwT[i] = dw[((l*64+co)*64+ci)*9 + kk];
    }
    int j = i - N1;
    if (j >= 0 && j < 7*10368) {
        int l = j / 10368, r = j - l*10368;
        int ik = r / 18, o = r - ik*18;
        int ci = ik / 9, k = ik - ci*9;
        owT[j] = ow[((l*18+o)*64+ci)*9 + k];
    }
}

// ---------------- staging helpers: 8ch x 20rows x 48cols tile ----------------
// 1920 float4 per slice, 256 threads -> up to 8 each.
__device__ __forceinline__ void d_issue(const float* __restrict__ x, int b, int ci0,
                                        int RLO, int CLO, int t, float4* rb)
{
#pragma unroll
    for (int k=0;k<8;k++){
        int f4i = t + (k<<8);
        float4 v = make_float4(0.f,0.f,0.f,0.f);
        if (f4i < 1920) {
            int ch = f4i/240, rem = f4i - ch*240;
            int row = rem/12, col4 = rem - row*12;
            int gy = RLO + row, gx = CLO + (col4<<2);
            if (gy>=0 && gy<128) {
                const float* sp = x + (((b<<6)+ci0+ch)<<14) + (gy<<7);
                if (gx>=0 && gx<=124) v = *(const float4*)(sp+gx);
                else {
                    float* pv = (float*)&v;
#pragma unroll
                    for (int e=0;e<4;e++){ int xx=gx+e; if (xx>=0 && xx<128) pv[e]=sp[xx]; }
                }
            }
        }
        rb[k]=v;
    }
}
__device__ __forceinline__ void d_commit(float* __restrict__ xs, int t, const float4* rb)
{
#pragma unroll
    for (int k=0;k<8;k++){
        int f4i = t + (k<<8);
        if (f4i < 1920){
            int ch = f4i/240, rem = f4i - ch*240;
            int row = rem/12, col4 = rem - row*12;
            *(float4*)(xs + ch*960 + row*48 + (col4<<2)) = rb[k];
        }
    }
}

// ---------------- fused offset-conv + deformable conv ----------------
// Block: 256 threads = 8 rows x 32 cols pixel tile. Grid: 4 wt * 16 ht * 4 b = 256.
__global__ __launch_bounds__(256,1) void fused_layer(
    const float* __restrict__ xin, const float* __restrict__ owT,
    const float* __restrict__ ob, const float* __restrict__ dwT,
    float* __restrict__ y)
{
    __shared__ float xt[2][7680];   // 2 x (8ch x 20 x 48) = 60 KB

    const int t = threadIdx.x, bid = blockIdx.x;
    const int wt = bid & 3, ht = (bid>>2)&15, b = bid>>6;
    const int w0 = wt*32, h0 = ht*8;
    const int r = t>>5, c = t&31;
    const int h = h0+r, w = w0+c;
    const int RLO = h0-5, CLO = w0-8;

    float4 rb[8];

    // ================= pass 1: offset conv =================
    float a18[18];
#pragma unroll
    for (int o=0;o<18;o++) a18[o]=0.f;

    d_issue(xin,b,0,RLO,CLO,t,rb);
    d_commit(xt[0],t,rb);
    __syncthreads();
#pragma unroll 1
    for (int s=0;s<8;s++){
        if (s<7) d_issue(xin,b,(s+1)*8,RLO,CLO,t,rb);
        const float* xs = xt[s&1];
#pragma unroll 1
        for (int kk=0;kk<9;kk++){
            int kh = kk/3, kw = kk - kh*3;
            int base = (r+4+kh)*48 + (c+7+kw);
#pragma unroll
            for (int ci=0;ci<8;ci++){
                float sv = xs[ci*960 + base];
                const float* wrow = owT + ((s*8+ci)*9+kk)*18;
#pragma unroll
                for (int o=0;o<18;o++) a18[o] += sv*wrow[o];
            }
        }
        if (s<7) d_commit(xt[(s+1)&1],t,rb);
        __syncthreads();
    }

    float offv[18];
#pragma unroll
    for (int q=0;q<18;q++) offv[q] = a18[q] + ob[q];

    // ================= pass 2: deformable conv =================
    float acc[64];
#pragma unroll
    for (int co=0;co<64;co++) acc[co]=0.f;

    d_issue(xin,b,0,RLO,CLO,t,rb);
    d_commit(xt[0],t,rb);
    __syncthreads();
#pragma unroll 1
    for (int s=0;s<8;s++){
        if (s<7) d_issue(xin,b,(s+1)*8,RLO,CLO,t,rb);
        const float* xs = xt[s&1];
#pragma unroll 1
        for (int kk=0;kk<9;kk++){
            int kh = kk/3, kw = kk - kh*3;
            float py = offv[2*kk]   + (float)(h - 1 + kh);
            float px = offv[2*kk+1] + (float)(w - 1 + kw);
            float fy = floorf(py), fx = floorf(px);
            float ly = py - fy, lx = px - fx;
            int y0 = (int)fy, x0 = (int)fx;
            int y1 = y0+1, x1 = x0+1;
            float vy0 = (y0>=0 && y0<128) ? 1.f : 0.f;
            float vy1 = (y1>=0 && y1<128) ? 1.f : 0.f;
            float vx0 = (x0>=0 && x0<128) ? 1.f : 0.f;
            float vx1 = (x1>=0 && x1<128) ? 1.f : 0.f;
            int y0c = min(max(y0,0),127), y1c = min(max(y1,0),127);
            int x0c = min(max(x0,0),127), x1c = min(max(x1,0),127);
            float w00 = (1.f-ly)*(1.f-lx)*vy0*vx0;
            float w01 = (1.f-ly)*lx*vy0*vx1;
            float w10 = ly*(1.f-lx)*vy1*vx0;
            float w11 = ly*lx*vy1*vx1;
            bool inb = (y0c>=RLO) && (y1c<=h0+14) && (x0c>=CLO) && (x1c<=w0+39);
            // clamped coords must be addressed independently: at image edges
            // x1c==x0c (or y1c==y0c), NOT x0c+1 — round-2 bug was a0+1 here.
            int ry0 = (y0c-RLO)*48, ry1 = (y1c-RLO)*48;
            int cx0 = x0c-CLO,      cx1 = x1c-CLO;
            if (inb) {
#pragma unroll
                for (int ci=0;ci<8;ci++){
                    const float* xc = xs + ci*960;
                    float sv = w00*xc[ry0+cx0] + w01*xc[ry0+cx1]
                             + w10*xc[ry1+cx0] + w11*xc[ry1+cx1];
                    const float* wrow = dwT + ((s*8+ci)*9+kk)*64;
#pragma unroll
                    for (int co=0;co<64;co++) acc[co] += sv*wrow[co];
                }
            } else {
#pragma unroll
                for (int ci=0;ci<8;ci++){
                    const float* xp = xin + (((b<<6)+s*8+ci)<<14);
                    float sv = w00*xp[(y0c<<7)+x0c] + w01*xp[(y0c<<7)+x1c]
                             + w10*xp[(y1c<<7)+x0c] + w11*xp[(y1c<<7)+x1c];
                    const float* wrow = dwT + ((s*8+ci)*9+kk)*64;
#pragma unroll
                    for (int co=0;co<64;co++) acc[co] += sv*wrow[co];
                }
            }
        }
        if (s<7) d_commit(xt[(s+1)&1],t,rb);
        __syncthreads();
    }

    // epilogue: y[b][co][h][w] = acc[co]
#pragma unroll
    for (int co=0;co<64;co++)
        y[(((b<<6)+co)<<14) + (h<<7) + w] = acc[co];
}

// ---------------- per-channel mean/var -> scale/shift ----------------
__global__ __launch_bounds__(256) void stats_kernel(
    const float* __restrict__ y, const float* __restrict__ gamma,
    const float* __restrict__ beta, float* __restrict__ stats)
{
    const int co = blockIdx.x, t = threadIdx.x;
    float s=0.f, s2=0.f;
    for (int b=0;b<4;b++) {
        const float4* p = (const float4*)(y + (((b<<6)+co)<<14));
        for (int i=t;i<4096;i+=256) {
            float4 v = p[i];
            s  += v.x+v.y+v.z+v.w;
            s2 += v.x*v.x+v.y*v.y+v.z*v.z+v.w*v.w;
        }
    }
    __shared__ float rs[256], rs2[256];
    rs[t]=s; rs2[t]=s2; __syncthreads();
    for (int k=128;k>0;k>>=1) {
        if (t<k){ rs[t]+=rs[t+k]; rs2[t]+=rs2[t+k]; }
        __syncthreads();
    }
    if (t==0) {
        float mean = rs[0] * (1.f/65536.f);
        float var  = rs2[0] * (1.f/65536.f) - mean*mean;
        float inv  = rsqrtf(var + EPS_);
        float sc   = gamma[co]*inv;
        stats[co]    = sc;
        stats[64+co] = beta[co] - mean*sc;
    }
}

// ---------------- normalize + ReLU + epilogue ----------------
// mode 0: out = relu(.)   mode 1: out = relu(.) + addsrc   mode 2: out += relu(.)
__global__ __launch_bounds__(256) void norm_kernel(
    const float* __restrict__ y, const float* __restrict__ stats,
    const float* __restrict__ addsrc, float* out, int mode)
{
    const int i4 = blockIdx.x*256 + threadIdx.x;
    const int ch = (i4 >> 12) & 63;
    const float sc = stats[ch], sh = stats[64+ch];
    float4 v = *(const float4*)&y[i4*4];
    float4 rr;
    rr.x = fmaxf(v.x*sc+sh, 0.f);
    rr.y = fmaxf(v.y*sc+sh, 0.f);
    rr.z = fmaxf(v.z*sc+sh, 0.f);
    rr.w = fmaxf(v.w*sc+sh, 0.f);
    if (mode == 1) {
        float4 a = *(const float4*)&addsrc[i4*4];
        rr.x+=a.x; rr.y+=a.y; rr.z+=a.z; rr.w+=a.w;
    } else if (mode == 2) {
        float4 o = *(const float4*)&out[i4*4];
        rr.x+=o.x; rr.y+=o.y; rr.z+=o.z; rr.w+=o.w;
    }
    *(float4*)&out[i4*4] = rr;
}

// ---------------- host orchestration ----------------
static void run_layer(int li, const float* in, float* ybuf, float* outbuf, int mode,
                      const float* addsrc, const float* ob, const float* g, const float* be,
                      const float* dwT, const float* owT, float* stats, hipStream_t stream)
{
    fused_layer<<<256, 256, 0, stream>>>(in, owT + li*10368, ob + li*18,
                                         dwT + li*36864, ybuf);
    stats_kernel<<<64, 256, 0, stream>>>(ybuf, g + li*64, be + li*64, stats);
    norm_kernel<<<4096, 256, 0, stream>>>(ybuf, stats, addsrc, outbuf, mode);
}

extern "C" void kernel_launch(void* const* d_in, const int* in_sizes, int n_in,
                              void* d_out, int out_size, void* d_ws, size_t ws_size,
                              hipStream_t stream)
{
    const float* x  = (const float*)d_in[0];
    const float* ow = (const float*)d_in[1];
    const float* ob = (const float*)d_in[2];
    const float* dw = (const float*)d_in[3];
    const float* g  = (const float*)d_in[4];
    const float* be = (const float*)d_in[5];
    float* out = (float*)d_out;

    float* P     = (float*)d_ws;
    float* Q     = P + NTOT;
    float* R     = Q + NTOT;
    float* stats = R + NTOT;
    float* dwT   = stats + 128;
    float* owT   = dwT + 7*36864;

    transpose_w<<<(7*36864 + 7*10368 + 255)/256, 256, 0, stream>>>(dw, ow, dwT, owT);

    // out_1 = L1(L0(x)) -> Q
    run_layer(0, x, P, P, 0, nullptr, ob, g, be, dwT, owT, stats, stream);
    run_layer(1, P, Q, Q, 0, nullptr, ob, g, be, dwT, owT, stats, stream);
    // s = out_1 + L4(x) -> R
    run_layer(4, x, R, R, 1, Q,       ob, g, be, dwT, owT, stats, stream);
    // out_1' = L3(L2(s)) -> Q
    run_layer(2, R, P, P, 0, nullptr, ob, g, be, dwT, owT, stats, stream);
    run_layer(3, P, Q, Q, 0, nullptr, ob, g, be, dwT, owT, stats, stream);
    // out = out_1' + L5(s) + L6(s)
    run_layer(5, R, P, out, 1, Q,     ob, g, be, dwT, owT, stats, stream);
    run_layer(6, R, P, out, 2, nullptr, ob, g, be, dwT, owT, stats, stream);
}

// Round 5
// 1100.179 us; speedup vs baseline: 3.6483x; 3.6483x over previous
//
#include <hip/hip_runtime.h>

#define NTOT 4194304
typedef __attribute__((ext_vector_type(4)))  short short4v;
typedef __attribute__((ext_vector_type(8)))  short short8v;
typedef __attribute__((ext_vector_type(4)))  float f32x4;

__device__ __forceinline__ ushort f2bf(float f){
    unsigned u = __float_as_uint(f);
    return (ushort)((u + 0x7FFFu + ((u>>16)&1u)) >> 16);
}
__device__ __forceinline__ float bf2f(ushort u){
    return __uint_as_float(((unsigned)u)<<16);
}

// ---------------- weight pack: per-lane MFMA B-fragment order, bf16 ----------------
// dwPk[l][ciq4][kkp5][koff2][cih2][jg2][co64][j4]
// owPk[l][ciq4][kkp5][koff2][cih2][jg2][co32][j4]
__global__ __launch_bounds__(256) void pack_w(
    const float* __restrict__ dw, const float* __restrict__ ow,
    ushort* __restrict__ dwPk, ushort* __restrict__ owPk,
    float* __restrict__ statsG)
{
    int i = blockIdx.x*256 + threadIdx.x;
    if (i < 286720) {
        int j = i&3, co = (i>>2)&63, jg=(i>>8)&1, cih=(i>>9)&1, koff=(i>>10)&1;
        int r = i>>11; int kkp = r%5; int r2 = r/5; int ciq = r2&3; int l = r2>>2;
        int kk = kkp*2+koff, ci = ciq*16 + cih*8 + jg*4 + j;
        float v = (kk<9)? dw[((l*64+co)*64+ci)*9+kk] : 0.f;
        dwPk[i] = f2bf(v);
    }
    if (i < 143360) {
        int j = i&3, co = (i>>2)&31, jg=(i>>7)&1, cih=(i>>8)&1, koff=(i>>9)&1;
        int r = i>>10; int kkp = r%5; int r2 = r/5; int ciq = r2&3; int l = r2>>2;
        int kk = kkp*2+koff, ci = ciq*16 + cih*8 + jg*4 + j;
        float v = (kk<9 && co<18)? ow[((l*18+co)*64+ci)*9+kk] : 0.f;
        owPk[i] = f2bf(v);
    }
    if (i < 7*1024) statsG[i] = 0.f;   // zero stats accumulators (capture-safe)
}

// kh/kw tables; index 9 clamps to kk=8 (ghost K-slots carry zero weights)
__constant__ int KHt[10] = {0,0,0,1,1,1,2,2,2,2};
__constant__ int KWt[10] = {0,1,2,0,1,2,0,1,2,2};

// ---------------- fused offset-conv (MFMA) + deformable conv (MFMA) ----------------
// Block: 256 thr = 4 waves; pixel tile 4 rows x 32 cols. Grid 512 = 4wt*32ht*4b.
// A-frag lane: pixel = p*16 + (lane&15); k-slot: kk=2kkp+(lane>>5),
// ci = ciq*16 + 8*((lane>>4)&1) + j.  C/D: col=lane&15, row=(lane>>4)*4+reg.
__global__ __launch_bounds__(256) void dcn_layer(
    const float* __restrict__ xin, const ushort* __restrict__ owPk,
    const float* __restrict__ ob, const ushort* __restrict__ dwPk,
    float* __restrict__ y, float* __restrict__ statsL)
{
    __shared__ char smem[24576];   // xt: 2 slices x [768 spatial][8ci] bf16
                                   // overlays: offl [128][20] f32, ytile [32][132] f32, red @16896

    const int t = threadIdx.x, lane = t&63, w = t>>6;
    const int l15 = lane&15, lg = lane>>4;
    const int cih = lg&1, koff = lane>>5;
    const int bid = blockIdx.x;
    const int wt = bid&3, ht = (bid>>2)&31, b = bid>>7;
    const int w0 = wt*32, h0 = ht*4;
    const int row = h0 + w;
    const int RLO = h0-6, CLO = w0-8;

    // ================= pass 1: offset conv via MFMA (A from global) =================
    f32x4 oacc[2][2];
#pragma unroll
    for (int p=0;p<2;p++)
#pragma unroll
        for (int q=0;q<2;q++) oacc[p][q] = (f32x4){0.f,0.f,0.f,0.f};

#pragma unroll 1
    for (int ciq=0; ciq<4; ++ciq) {
#pragma unroll
        for (int kkp=0; kkp<5; ++kkp) {
            const int kkA = 2*kkp, kkB = (2*kkp+1>8)?8:(2*kkp+1);
            int kh = koff ? KHt[kkB] : KHt[kkA];
            int kw = koff ? KWt[kkB] : KWt[kkA];
            int gy = row + kh - 1;
            bool vy = ((unsigned)gy < 128u);
            const float* xpl = xin + (((b<<6) + ciq*16 + cih*8)<<14) + gy*128;
            short8v afr[2];
#pragma unroll
            for (int p=0;p<2;p++){
                int gx = w0 + p*16 + l15 + kw - 1;
                bool ok = vy && ((unsigned)gx < 128u);
                const float* xp = xpl + gx;
#pragma unroll
                for (int j=0;j<8;j++){
                    float v = ok ? xp[j<<14] : 0.f;
                    afr[p][j] = (short)f2bf(v);
                }
            }
            const ushort* wop = owPk + ciq*5120 + kkp*1024 + koff*512 + cih*256;
#pragma unroll
            for (int q=0;q<2;q++){
                short4v b0 = *(const short4v*)(wop +       (q*16+l15)*4);
                short4v b1 = *(const short4v*)(wop + 128 + (q*16+l15)*4);
                short8v bb = __builtin_shufflevector(b0,b1,0,1,2,3,4,5,6,7);
#pragma unroll
                for (int p=0;p<2;p++)
                    oacc[p][q] = __builtin_amdgcn_mfma_f32_16x16x32_bf16(afr[p], bb, oacc[p][q], 0,0,0);
            }
        }
    }

    // redistribute offsets through LDS: offl[pix128][20]; ONLY o<18 (ghost cols
    // o=18..31 would overflow the stride-20 row and clobber neighbor pixels!)
    float* offl = (float*)smem;
    float biasq[2];
#pragma unroll
    for (int q=0;q<2;q++){ int o = q*16+l15; biasq[q] = (o<18)? ob[o] : 0.f; }
#pragma unroll
    for (int p=0;p<2;p++)
#pragma unroll
        for (int q=0;q<2;q++){
            int o = q*16+l15;
            if (o < 18) {
#pragma unroll
                for (int r=0;r<4;r++){
                    int pix = w*32 + p*16 + lg*4 + r;
                    offl[pix*20 + o] = oacc[p][q][r] + biasq[q];
                }
            }
        }
    __syncthreads();
    float ofv[36];
#pragma unroll
    for (int p=0;p<2;p++){
        int pix = w*32 + p*16 + l15;
#pragma unroll
        for (int o=0;o<18;o++) ofv[p*18+o] = offl[pix*20 + o];
    }
    __syncthreads();

    // ================= pass 2: deformable conv via MFMA =================
    f32x4 acc[2][4];
#pragma unroll
    for (int p=0;p<2;p++)
#pragma unroll
        for (int q=0;q<4;q++) acc[p][q] = (f32x4){0.f,0.f,0.f,0.f};

    ushort* xt = (ushort*)smem;

#pragma unroll 1
    for (int ciq=0; ciq<4; ++ciq) {
        // ---- stage 16 ci as bf16, layout [slice2][spatial 16x48][ci8] ----
#pragma unroll
        for (int i=0;i<12;i++){
            int d = i*256 + t;               // 0..3071
            int cq = d/768;                  // 0..3 (4 ci each)
            int spatial = d - cq*768;
            int rowt = spatial/48, colt = spatial - rowt*48;
            int gy = RLO + rowt, gx = CLO + colt;
            bool ok  = ((unsigned)gy < 128u) && ((unsigned)gx < 128u);
            const float* gp = xin + (((b<<6) + ciq*16 + cq*4)<<14) + gy*128 + gx;
            short4v pk;
#pragma unroll
            for (int e=0;e<4;e++){
                float v = ok ? gp[e<<14] : 0.f;
                pk[e] = (short)f2bf(v);
            }
            *(short4v*)(xt + (cq>>1)*6144 + spatial*8 + (cq&1)*4) = pk;
        }
        __syncthreads();

#pragma unroll
        for (int kkp=0; kkp<5; ++kkp) {
            const int kkA = 2*kkp, kkB = (2*kkp+1>8)?8:(2*kkp+1);
            int kh = koff ? KHt[kkB] : KHt[kkA];
            int kw = koff ? KWt[kkB] : KWt[kkA];
            short8v afr[2];
#pragma unroll
            for (int p=0;p<2;p++){
                float dy = koff ? ofv[p*18+2*kkB]   : ofv[p*18+2*kkA];
                float dx = koff ? ofv[p*18+2*kkB+1] : ofv[p*18+2*kkA+1];
                float py = (float)(row + kh - 1) + dy;
                float px = (float)(w0 + p*16 + l15 + kw - 1) + dx;
                float fy = floorf(py), fx = floorf(px);
                float ly = py - fy, lx = px - fx;
                int y0 = (int)fy, x0 = (int)fx;
                int y1 = y0+1, x1 = x0+1;
                bool vy0 = ((unsigned)y0<128u), vy1 = ((unsigned)y1<128u);
                bool vx0 = ((unsigned)x0<128u), vx1 = ((unsigned)x1<128u);
                int y0c = min(max(y0,0),127), y1c = min(max(y1,0),127);
                int x0c = min(max(x0,0),127), x1c = min(max(x1,0),127);
                int r0 = y0c-RLO, r1 = y1c-RLO, c0 = x0c-CLO, c1 = x1c-CLO;
                bool ty0 = ((unsigned)r0<16u), ty1 = ((unsigned)r1<16u);
                bool tx0 = ((unsigned)c0<48u), tx1 = ((unsigned)c1<48u);
                // image-valid weights vs tile-usable weights
                float g00 = (vy0&&vx0) ? (1.f-ly)*(1.f-lx) : 0.f;
                float g01 = (vy0&&vx1) ? (1.f-ly)*lx       : 0.f;
                float g10 = (vy1&&vx0) ? ly*(1.f-lx)       : 0.f;
                float g11 = (vy1&&vx1) ? ly*lx             : 0.f;
                float f00 = (ty0&&tx0) ? g00 : 0.f;
                float f01 = (ty0&&tx1) ? g01 : 0.f;
                float f10 = (ty1&&tx0) ? g10 : 0.f;
                float f11 = (ty1&&tx1) ? g11 : 0.f;
                int rc0 = min(max(r0,0),15), rc1 = min(max(r1,0),15);
                int cc0 = min(max(c0,0),47), cc1 = min(max(c1,0),47);
                const ushort* xs = xt + cih*6144;
                short8v q00 = *(const short8v*)(xs + (rc0*48+cc0)*8);
                short8v q01 = *(const short8v*)(xs + (rc0*48+cc1)*8);
                short8v q10 = *(const short8v*)(xs + (rc1*48+cc0)*8);
                short8v q11 = *(const short8v*)(xs + (rc1*48+cc1)*8);
                float sv[8];
#pragma unroll
                for (int j=0;j<8;j++)
                    sv[j] = f00*bf2f((ushort)q00[j]) + f01*bf2f((ushort)q01[j])
                          + f10*bf2f((ushort)q10[j]) + f11*bf2f((ushort)q11[j]);
                // rare fallback: in-image but out-of-tile corners read global
                float r00 = g00-f00, r01 = g01-f01, r10 = g10-f10, r11 = g11-f11;
                if (r00+r01+r10+r11 > 0.f) {
                    const float* xg = xin + (((b<<6) + ciq*16 + cih*8)<<14);
                    int a00 = (y0c<<7)+x0c, a01 = (y0c<<7)+x1c;
                    int a10 = (y1c<<7)+x0c, a11 = (y1c<<7)+x1c;
#pragma unroll
                    for (int j=0;j<8;j++){
                        int o = j<<14;
                        sv[j] += r00*xg[a00+o] + r01*xg[a01+o]
                               + r10*xg[a10+o] + r11*xg[a11+o];
                    }
                }
#pragma unroll
                for (int j=0;j<8;j++) afr[p][j] = (short)f2bf(sv[j]);
            }
            const ushort* wp = dwPk + ciq*10240 + kkp*2048 + koff*1024 + cih*512;
#pragma unroll
            for (int q=0;q<4;q++){
                short4v b0 = *(const short4v*)(wp +       (q*16+l15)*4);
                short4v b1 = *(const short4v*)(wp + 256 + (q*16+l15)*4);
                short8v bb = __builtin_shufflevector(b0,b1,0,1,2,3,4,5,6,7);
                acc[0][q] = __builtin_amdgcn_mfma_f32_16x16x32_bf16(afr[0], bb, acc[0][q], 0,0,0);
                acc[1][q] = __builtin_amdgcn_mfma_f32_16x16x32_bf16(afr[1], bb, acc[1][q], 0,0,0);
            }
        }
        __syncthreads();
    }

    // ================= epilogue: transpose via LDS, store, stats =================
    float* yt  = (float*)smem;              // [32][132]
    float* red = (float*)(smem + 16896);    // [512]
#pragma unroll 1
    for (int half=0; half<2; ++half){
#pragma unroll
        for (int p=0;p<2;p++)
#pragma unroll
            for (int qq=0;qq<2;qq++){
                int q = half*2+qq;
                *(f32x4*)(yt + (qq*16+l15)*132 + w*32 + p*16 + lg*4) = acc[p][q];
            }
        __syncthreads();
#pragma unroll
        for (int i=0;i<4;i++){
            int f4 = i*256 + t;
            int co32 = f4>>5, p4 = (f4&31)*4;
            f32x4 v = *(const f32x4*)(yt + co32*132 + p4);
            *(f32x4*)(y + (((b<<6) + half*32 + co32)<<14) + (h0 + (p4>>5))*128 + w0 + (p4&31)) = v;
        }
        {
            float s=0.f, s2=0.f;
            int co = t&31, seg = t>>5;
            const float* bp = yt + co*132 + seg*16;
#pragma unroll
            for (int qd=0;qd<16;qd++){ float v = bp[qd]; s += v; s2 += v*v; }
            red[t] = s; red[256+t] = s2;
        }
        __syncthreads();
        if (t < 64){
            int vv = t>>5, cc = t&31;
            float a = 0.f;
#pragma unroll
            for (int g=0;g<8;g++) a += red[vv*256 + g*32 + cc];
            atomicAdd(statsL + (bid&7)*128 + vv*64 + half*32 + cc, a);
        }
        __syncthreads();
    }
}

// ---------------- normalize + ReLU + epilogue, stats finalized inline ----------------
// mode 0: out = relu(.)   mode 1: out = relu(.) + addsrc   mode 2: out += relu(.)
__global__ __launch_bounds__(256) void norm2(
    const float* __restrict__ yv, const float* __restrict__ statsL,
    const float* __restrict__ gamma, const float* __restrict__ beta,
    const float* __restrict__ addsrc, float* out, int mode)
{
    const int i4 = blockIdx.x*256 + threadIdx.x;
    const int ch = (i4 >> 12) & 63;
    float sum=0.f, ssq=0.f;
#pragma unroll
    for (int s=0;s<8;s++){ sum += statsL[s*128+ch]; ssq += statsL[s*128+64+ch]; }
    float mean = sum*(1.f/65536.f);
    float var  = ssq*(1.f/65536.f) - mean*mean;
    float inv  = rsqrtf(var + 1e-5f);
    float sc = gamma[ch]*inv, sh = beta[ch] - mean*sc;
    float4 v = *(const float4*)&yv[i4*4];
    float4 rr;
    rr.x = fmaxf(v.x*sc+sh, 0.f);
    rr.y = fmaxf(v.y*sc+sh, 0.f);
    rr.z = fmaxf(v.z*sc+sh, 0.f);
    rr.w = fmaxf(v.w*sc+sh, 0.f);
    if (mode == 1) {
        float4 a = *(const float4*)&addsrc[i4*4];
        rr.x+=a.x; rr.y+=a.y; rr.z+=a.z; rr.w+=a.w;
    } else if (mode == 2) {
        float4 o = *(const float4*)&out[i4*4];
        rr.x+=o.x; rr.y+=o.y; rr.z+=o.z; rr.w+=o.w;
    }
    *(float4*)&out[i4*4] = rr;
}

// ---------------- host orchestration ----------------
extern "C" void kernel_launch(void* const* d_in, const int* in_sizes, int n_in,
                              void* d_out, int out_size, void* d_ws, size_t ws_size,
                              hipStream_t stream)
{
    const float* x  = (const float*)d_in[0];
    const float* ow = (const float*)d_in[1];
    const float* ob = (const float*)d_in[2];
    const float* dw = (const float*)d_in[3];
    const float* g  = (const float*)d_in[4];
    const float* be = (const float*)d_in[5];
    float* out = (float*)d_out;

    float*  yb     = (float*)d_ws;
    float*  P      = yb + NTOT;
    float*  Q      = P + NTOT;
    float*  statsG = Q + NTOT;               // 7*1024 f32
    ushort* dwPk   = (ushort*)(statsG + 7*1024);
    ushort* owPk   = dwPk + 286720;

    pack_w<<<1120, 256, 0, stream>>>(dw, ow, dwPk, owPk, statsG);

    auto L = [&](int l, const float* in, float* dst, int mode, const float* adds){
        dcn_layer<<<512, 256, 0, stream>>>(in, owPk + l*20480, ob + l*18,
                                           dwPk + l*40960, yb, statsG + l*1024);
        norm2<<<4096, 256, 0, stream>>>(yb, statsG + l*1024, g + l*64, be + l*64,
                                        adds, dst, mode);
    };

    L(0, x, P,   0, nullptr);   // P = L0(x)
    L(1, P, P,   0, nullptr);   // P = L1(P)            (out_1)
    L(4, x, Q,   1, P);         // Q = L4(x) + P        (out_sum_1)
    L(2, Q, P,   0, nullptr);   // P = L2(Q)
    L(3, P, out, 0, nullptr);   // out = L3(P)
    L(5, Q, out, 2, nullptr);   // out += L5(Q)
    L(6, Q, out, 2, nullptr);   // out += L6(Q)
}

// Round 6
// 687.200 us; speedup vs baseline: 5.8407x; 1.6010x over previous
//
#include <hip/hip_runtime.h>

#define NTOT 4194304
typedef __attribute__((ext_vector_type(4)))  short short4v;
typedef __attribute__((ext_vector_type(8)))  short short8v;
typedef __attribute__((ext_vector_type(4)))  float f32x4;

__device__ __forceinline__ ushort f2bf(float f){
    unsigned u = __float_as_uint(f);
    return (ushort)((u + 0x7FFFu + ((u>>16)&1u)) >> 16);
}
__device__ __forceinline__ float bf2f(ushort u){
    return __uint_as_float(((unsigned)u)<<16);
}

// ---------------- weight pack: per-lane MFMA B-fragment order, bf16 ----------------
// dwPk[l][ciq4][kkp5][koff2][cih2][jg2][co64][j4]
// owPk[l][ciq4][kkp5][koff2][cih2][jg2][co32][j4]
__global__ __launch_bounds__(256) void pack_w(
    const float* __restrict__ dw, const float* __restrict__ ow,
    ushort* __restrict__ dwPk, ushort* __restrict__ owPk,
    float* __restrict__ statsG)
{
    int i = blockIdx.x*256 + threadIdx.x;
    if (i < 286720) {
        int j = i&3, co = (i>>2)&63, jg=(i>>8)&1, cih=(i>>9)&1, koff=(i>>10)&1;
        int r = i>>11; int kkp = r%5; int r2 = r/5; int ciq = r2&3; int l = r2>>2;
        int kk = kkp*2+koff, ci = ciq*16 + cih*8 + jg*4 + j;
        float v = (kk<9)? dw[((l*64+co)*64+ci)*9+kk] : 0.f;
        dwPk[i] = f2bf(v);
    }
    if (i < 143360) {
        int j = i&3, co = (i>>2)&31, jg=(i>>7)&1, cih=(i>>8)&1, koff=(i>>9)&1;
        int r = i>>10; int kkp = r%5; int r2 = r/5; int ciq = r2&3; int l = r2>>2;
        int kk = kkp*2+koff, ci = ciq*16 + cih*8 + jg*4 + j;
        float v = (kk<9 && co<18)? ow[((l*18+co)*64+ci)*9+kk] : 0.f;
        owPk[i] = f2bf(v);
    }
    if (i < 7*1024) statsG[i] = 0.f;   // zero stats accumulators (capture-safe)
}

// kh/kw tables; index 9 clamps to kk=8 (ghost K-slots carry zero weights)
__constant__ int KHt[10] = {0,0,0,1,1,1,2,2,2,2};
__constant__ int KWt[10] = {0,1,2,0,1,2,0,1,2,2};

// ---------------- fused offset-conv + deformable conv, single LDS stage ----------------
// Block: 512 thr = 8 waves; tile 8 rows x 32 cols. Grid 256, XCD-bijective decode.
// LDS xt: [spatial 20x48][ci 64] bf16, 16B slot index XOR-swizzled by (spatial&7).
// A-frag lane: pixel = p*16+(lane&15); k-slot: kk=2kkp+(lane>>5), ci=ciq*16+8*((lane>>4)&1)+j.
// C/D: col=lane&15 (co), row=(lane>>4)*4+reg (pix).
__global__ __launch_bounds__(512,2) void dcn_layer(
    const float* __restrict__ xin, const ushort* __restrict__ owPk,
    const float* __restrict__ ob, const ushort* __restrict__ dwPk,
    float* __restrict__ y, float* __restrict__ statsL)
{
    __shared__ __align__(16) char smem[143360];
    ushort* xt  = (ushort*)smem;                 // 960 spatial * 128B = 122880 B
    float* offl = (float*)(smem + 122880);       // [256][20] = 20480 B

    const int t = threadIdx.x, lane = t&63, w = t>>6;
    const int l15 = lane&15, lg = lane>>4;
    const int cih = lg&1, koff = lane>>5;
    const int bid = blockIdx.x;
    // XCD-aware bijective decode: xcd=bid&7 owns half an image (1MB < 4MB L2)
    const int xcd = bid&7, idx = bid>>3;
    const int b = xcd>>1, vh = xcd&1;
    const int ht = vh*8 + (idx>>2), wt = idx&3;
    const int w0 = wt*32, h0 = ht*8;
    const int row = h0 + w;
    const int RLO = h0-6, CLO = w0-8;

    // ================= stage full 64-ci halo tile (once) =================
#pragma unroll 1
    for (int i=0;i<30;i++){
        int d = i*512 + t;                 // 0..15359 : (cq 0..15) x (spatial 0..959)
        int cq = d/960, spatial = d - cq*960;
        int rowt = spatial/48, colt = spatial - rowt*48;
        int gy = RLO+rowt, gx = CLO+colt;
        bool ok = ((unsigned)gy<128u) && ((unsigned)gx<128u);
        const float* gp = xin + (((b<<6)+(cq<<2))<<14) + (gy<<7) + gx;
        short4v pk;
#pragma unroll
        for (int e=0;e<4;e++){
            float v = ok ? gp[e<<14] : 0.f;
            pk[e] = (short)f2bf(v);
        }
        int byt = spatial*128 + (((cq>>1)^(spatial&7))<<4) + ((cq&1)<<3);
        *(short4v*)(smem + byt) = pk;
    }
    __syncthreads();

    // ================= pass 1: offset conv via MFMA (A from LDS) =================
    f32x4 oacc[2][2];
#pragma unroll
    for (int p=0;p<2;p++)
#pragma unroll
        for (int q=0;q<2;q++) oacc[p][q] = (f32x4){0.f,0.f,0.f,0.f};

#pragma unroll 1
    for (int ciq=0; ciq<4; ++ciq) {
#pragma unroll
        for (int kkp=0; kkp<5; ++kkp) {
            const int kkA = 2*kkp, kkB = (2*kkp+1>8)?8:(2*kkp+1);
            int kh = koff ? KHt[kkB] : KHt[kkA];
            int kw = koff ? KWt[kkB] : KWt[kkA];
            short8v afr[2];
#pragma unroll
            for (int p=0;p<2;p++){
                int colt = p*16 + l15 + kw + 7;     // (w0+p*16+l15+kw-1) - CLO
                int rowt = w + 5 + kh;              // (row+kh-1) - RLO
                int sp = rowt*48 + colt;
                int byt = sp*128 + ((((ciq<<1)|cih) ^ (sp&7))<<4);
                afr[p] = *(const short8v*)(smem + byt);
            }
            const ushort* wop = owPk + ciq*5120 + kkp*1024 + koff*512 + cih*256;
#pragma unroll
            for (int q=0;q<2;q++){
                short4v b0 = *(const short4v*)(wop +       (q*16+l15)*4);
                short4v b1 = *(const short4v*)(wop + 128 + (q*16+l15)*4);
                short8v bb = __builtin_shufflevector(b0,b1,0,1,2,3,4,5,6,7);
#pragma unroll
                for (int p=0;p<2;p++)
                    oacc[p][q] = __builtin_amdgcn_mfma_f32_16x16x32_bf16(afr[p], bb, oacc[p][q], 0,0,0);
            }
        }
    }

    // redistribute offsets: offl[pix 256][20]; only o<18 (stride-20 overflow guard)
    float biasq[2];
#pragma unroll
    for (int q=0;q<2;q++){ int o = q*16+l15; biasq[q] = (o<18)? ob[o] : 0.f; }
#pragma unroll
    for (int p=0;p<2;p++)
#pragma unroll
        for (int q=0;q<2;q++){
            int o = q*16+l15;
            if (o < 18) {
#pragma unroll
                for (int r=0;r<4;r++){
                    int pix = w*32 + p*16 + lg*4 + r;
                    offl[pix*20 + o] = oacc[p][q][r] + biasq[q];
                }
            }
        }
    __syncthreads();
    float ofv[36];
#pragma unroll
    for (int p=0;p<2;p++){
        int pix = w*32 + p*16 + l15;
#pragma unroll
        for (int o=0;o<18;o++) ofv[p*18+o] = offl[pix*20 + o];
    }

    // ================= pass 2: deformable conv via MFMA (no restage, no syncs) =================
    f32x4 acc[2][4];
#pragma unroll
    for (int p=0;p<2;p++)
#pragma unroll
        for (int q=0;q<4;q++) acc[p][q] = (f32x4){0.f,0.f,0.f,0.f};

#pragma unroll 1
    for (int ciq=0; ciq<4; ++ciq) {
#pragma unroll
        for (int kkp=0; kkp<5; ++kkp) {
            const int kkA = 2*kkp, kkB = (2*kkp+1>8)?8:(2*kkp+1);
            int kh = koff ? KHt[kkB] : KHt[kkA];
            int kw = koff ? KWt[kkB] : KWt[kkA];
            short8v afr[2];
#pragma unroll
            for (int p=0;p<2;p++){
                float dy = koff ? ofv[p*18+2*kkB]   : ofv[p*18+2*kkA];
                float dx = koff ? ofv[p*18+2*kkB+1] : ofv[p*18+2*kkA+1];
                float py = (float)(row + kh - 1) + dy;
                float px = (float)(w0 + p*16 + l15 + kw - 1) + dx;
                float fy = floorf(py), fx = floorf(px);
                float ly = py - fy, lx = px - fx;
                int y0 = (int)fy, x0 = (int)fx;
                int y1 = y0+1, x1 = x0+1;
                bool vy0 = ((unsigned)y0<128u), vy1 = ((unsigned)y1<128u);
                bool vx0 = ((unsigned)x0<128u), vx1 = ((unsigned)x1<128u);
                int y0c = min(max(y0,0),127), y1c = min(max(y1,0),127);
                int x0c = min(max(x0,0),127), x1c = min(max(x1,0),127);
                int r0 = y0c-RLO, r1 = y1c-RLO, c0 = x0c-CLO, c1 = x1c-CLO;
                bool ty0 = ((unsigned)r0<20u), ty1 = ((unsigned)r1<20u);
                bool tx0 = ((unsigned)c0<48u), tx1 = ((unsigned)c1<48u);
                float g00 = (vy0&&vx0) ? (1.f-ly)*(1.f-lx) : 0.f;
                float g01 = (vy0&&vx1) ? (1.f-ly)*lx       : 0.f;
                float g10 = (vy1&&vx0) ? ly*(1.f-lx)       : 0.f;
                float g11 = (vy1&&vx1) ? ly*lx             : 0.f;
                float f00 = (ty0&&tx0) ? g00 : 0.f;
                float f01 = (ty0&&tx1) ? g01 : 0.f;
                float f10 = (ty1&&tx0) ? g10 : 0.f;
                float f11 = (ty1&&tx1) ? g11 : 0.f;
                int rc0 = min(max(r0,0),19), rc1 = min(max(r1,0),19);
                int cc0 = min(max(c0,0),47), cc1 = min(max(c1,0),47);
                int s00 = rc0*48+cc0, s01 = rc0*48+cc1, s10 = rc1*48+cc0, s11 = rc1*48+cc1;
                int slot = (ciq<<1)|cih;
                short8v q00 = *(const short8v*)(smem + s00*128 + ((slot^(s00&7))<<4));
                short8v q01 = *(const short8v*)(smem + s01*128 + ((slot^(s01&7))<<4));
                short8v q10 = *(const short8v*)(smem + s10*128 + ((slot^(s10&7))<<4));
                short8v q11 = *(const short8v*)(smem + s11*128 + ((slot^(s11&7))<<4));
                float sv[8];
#pragma unroll
                for (int j=0;j<8;j++)
                    sv[j] = f00*bf2f((ushort)q00[j]) + f01*bf2f((ushort)q01[j])
                          + f10*bf2f((ushort)q10[j]) + f11*bf2f((ushort)q11[j]);
                // rare fallback: in-image but out-of-tile corners read global fp32
                float r00 = g00-f00, r01 = g01-f01, r10 = g10-f10, r11 = g11-f11;
                if (r00+r01+r10+r11 > 0.f) {
                    const float* xg = xin + (((b<<6) + ciq*16 + cih*8)<<14);
                    int a00 = (y0c<<7)+x0c, a01 = (y0c<<7)+x1c;
                    int a10 = (y1c<<7)+x0c, a11 = (y1c<<7)+x1c;
#pragma unroll
                    for (int j=0;j<8;j++){
                        int o = j<<14;
                        sv[j] += r00*xg[a00+o] + r01*xg[a01+o]
                               + r10*xg[a10+o] + r11*xg[a11+o];
                    }
                }
#pragma unroll
                for (int j=0;j<8;j++) afr[p][j] = (short)f2bf(sv[j]);
            }
            const ushort* wp = dwPk + ciq*10240 + kkp*2048 + koff*1024 + cih*512;
#pragma unroll
            for (int q=0;q<4;q++){
                short4v b0 = *(const short4v*)(wp +       (q*16+l15)*4);
                short4v b1 = *(const short4v*)(wp + 256 + (q*16+l15)*4);
                short8v bb = __builtin_shufflevector(b0,b1,0,1,2,3,4,5,6,7);
                acc[0][q] = __builtin_amdgcn_mfma_f32_16x16x32_bf16(afr[0], bb, acc[0][q], 0,0,0);
                acc[1][q] = __builtin_amdgcn_mfma_f32_16x16x32_bf16(afr[1], bb, acc[1][q], 0,0,0);
            }
        }
    }

    // ================= epilogue: LDS transpose, store, stats (fully unrolled: no spill) =================
    float* yt  = (float*)smem;               // [32 co][260] = 33280 B (overlays xt)
    float* red = (float*)(smem + 33280);     // 1024 f32
#pragma unroll
    for (int half=0; half<2; ++half){
        __syncthreads();   // iter0: pass-2 xt reads done; iter1: prev stats reads done
#pragma unroll
        for (int p=0;p<2;p++)
#pragma unroll
            for (int qq=0;qq<2;qq++)
                *(f32x4*)(yt + (qq*16+l15)*260 + w*32 + p*16 + lg*4) = acc[p][half*2+qq];
        __syncthreads();
#pragma unroll
        for (int i=0;i<4;i++){
            int f4 = i*512 + t;
            int co = f4>>6, px4 = (f4&63)<<2;
            f32x4 v = *(const f32x4*)(yt + co*260 + px4);
            *(f32x4*)(y + (((b<<6) + half*32 + co)<<14) + (h0 + (px4>>5))*128 + w0 + (px4&31)) = v;
        }
        {
            float s=0.f, s2=0.f;
            int co = t&31, seg = t>>5;
            const float* bp = yt + co*260 + seg*16;
#pragma unroll
            for (int qd=0;qd<16;qd++){ float v = bp[qd]; s += v; s2 += v*v; }
            red[seg*32+co] = s; red[512 + seg*32+co] = s2;
        }
        __syncthreads();
        if (t < 64){
            int vv = t>>5, cc = t&31;
            float a = 0.f;
#pragma unroll
            for (int g=0;g<16;g++) a += red[vv*512 + g*32 + cc];
            atomicAdd(statsL + (bid&7)*128 + vv*64 + half*32 + cc, a);
        }
    }
}

// ---------------- normalize + ReLU + epilogue, stats finalized inline ----------------
// mode 0: out = relu(.)   mode 1: out = relu(.) + addsrc   mode 2: out += relu(.)
__global__ __launch_bounds__(256) void norm2(
    const float* __restrict__ yv, const float* __restrict__ statsL,
    const float* __restrict__ gamma, const float* __restrict__ beta,
    const float* __restrict__ addsrc, float* out, int mode)
{
    const int i4 = blockIdx.x*256 + threadIdx.x;
    const int ch = (i4 >> 12) & 63;
    float sum=0.f, ssq=0.f;
#pragma unroll
    for (int s=0;s<8;s++){ sum += statsL[s*128+ch]; ssq += statsL[s*128+64+ch]; }
    float mean = sum*(1.f/65536.f);
    float var  = ssq*(1.f/65536.f) - mean*mean;
    float inv  = rsqrtf(var + 1e-5f);
    float sc = gamma[ch]*inv, sh = beta[ch] - mean*sc;
    float4 v = *(const float4*)&yv[i4*4];
    float4 rr;
    rr.x = fmaxf(v.x*sc+sh, 0.f);
    rr.y = fmaxf(v.y*sc+sh, 0.f);
    rr.z = fmaxf(v.z*sc+sh, 0.f);
    rr.w = fmaxf(v.w*sc+sh, 0.f);
    if (mode == 1) {
        float4 a = *(const float4*)&addsrc[i4*4];
        rr.x+=a.x; rr.y+=a.y; rr.z+=a.z; rr.w+=a.w;
    } else if (mode == 2) {
        float4 o = *(const float4*)&out[i4*4];
        rr.x+=o.x; rr.y+=o.y; rr.z+=o.z; rr.w+=o.w;
    }
    *(float4*)&out[i4*4] = rr;
}

// ---------------- host orchestration ----------------
extern "C" void kernel_launch(void* const* d_in, const int* in_sizes, int n_in,
                              void* d_out, int out_size, void* d_ws, size_t ws_size,
                              hipStream_t stream)
{
    const float* x  = (const float*)d_in[0];
    const float* ow = (const float*)d_in[1];
    const float* ob = (const float*)d_in[2];
    const float* dw = (const float*)d_in[3];
    const float* g  = (const float*)d_in[4];
    const float* be = (const float*)d_in[5];
    float* out = (float*)d_out;

    float*  yb     = (float*)d_ws;
    float*  P      = yb + NTOT;
    float*  Q      = P + NTOT;
    float*  statsG = Q + NTOT;               // 7*1024 f32
    ushort* dwPk   = (ushort*)(statsG + 7*1024);
    ushort* owPk   = dwPk + 286720;

    pack_w<<<1120, 256, 0, stream>>>(dw, ow, dwPk, owPk, statsG);

    auto L = [&](int l, const float* in, float* dst, int mode, const float* adds){
        dcn_layer<<<256, 512, 0, stream>>>(in, owPk + l*20480, ob + l*18,
                                           dwPk + l*40960, yb, statsG + l*1024);
        norm2<<<4096, 256, 0, stream>>>(yb, statsG + l*1024, g + l*64, be + l*64,
                                        adds, dst, mode);
    };

    L(0, x, P,   0, nullptr);   // P = L0(x)
    L(1, P, P,   0, nullptr);   // P = L1(P)            (out_1)
    L(4, x, Q,   1, P);         // Q = L4(x) + P        (out_sum_1)
    L(2, Q, P,   0, nullptr);   // P = L2(Q)
    L(3, P, out, 0, nullptr);   // out = L3(P)
    L(5, Q, out, 2, nullptr);   // out += L5(Q)
    L(6, Q, out, 2, nullptr);   // out += L6(Q)
}

// Round 7
// 594.037 us; speedup vs baseline: 6.7567x; 1.1568x over previous
//
#include <hip/hip_runtime.h>

#define NTOT 4194304
typedef __attribute__((ext_vector_type(4)))  short short4v;
typedef __attribute__((ext_vector_type(8)))  short short8v;
typedef __attribute__((ext_vector_type(4)))  float f32x4;

__device__ __forceinline__ ushort f2bf(float f){
    unsigned u = __float_as_uint(f);
    return (ushort)((u + 0x7FFFu + ((u>>16)&1u)) >> 16);
}
__device__ __forceinline__ float bf2f(ushort u){
    return __uint_as_float(((unsigned)u)<<16);
}

// ---------------- weight pack: per-lane MFMA B-fragment order, bf16 ----------------
// dwPk[l][ciq4][kkp5][koff2][cih2][jg2][co64][j4]
// owPk[l][ciq4][kkp5][koff2][cih2][jg2][co32][j4]
__global__ __launch_bounds__(256) void pack_w(
    const float* __restrict__ dw, const float* __restrict__ ow,
    ushort* __restrict__ dwPk, ushort* __restrict__ owPk,
    float* __restrict__ statsG)
{
    int i = blockIdx.x*256 + threadIdx.x;
    if (i < 286720) {
        int j = i&3, co = (i>>2)&63, jg=(i>>8)&1, cih=(i>>9)&1, koff=(i>>10)&1;
        int r = i>>11; int kkp = r%5; int r2 = r/5; int ciq = r2&3; int l = r2>>2;
        int kk = kkp*2+koff, ci = ciq*16 + cih*8 + jg*4 + j;
        float v = (kk<9)? dw[((l*64+co)*64+ci)*9+kk] : 0.f;
        dwPk[i] = f2bf(v);
    }
    if (i < 143360) {
        int j = i&3, co = (i>>2)&31, jg=(i>>7)&1, cih=(i>>8)&1, koff=(i>>9)&1;
        int r = i>>10; int kkp = r%5; int r2 = r/5; int ciq = r2&3; int l = r2>>2;
        int kk = kkp*2+koff, ci = ciq*16 + cih*8 + jg*4 + j;
        float v = (kk<9 && co<18)? ow[((l*18+co)*64+ci)*9+kk] : 0.f;
        owPk[i] = f2bf(v);
    }
    if (i < 7*1024) statsG[i] = 0.f;   // zero stats accumulators (capture-safe)
}

// kh/kw tables; index 9 clamps to kk=8 (ghost K-slots carry zero weights)
__constant__ int KHt[10] = {0,0,0,1,1,1,2,2,2,2};
__constant__ int KWt[10] = {0,1,2,0,1,2,0,1,2,2};

// ---------------- fused offset-conv + deformable conv, single LDS stage ----------------
// Block: 512 thr = 8 waves; tile 8 rows x 32 cols. Grid 256, XCD-bijective decode.
// LDS xt: [spatial 20x48][ci 64] bf16, 16B slot index XOR-swizzled by (spatial&7).
// A-frag lane: pixel = p*16+(lane&15); k-slot: kk=2kkp+(lane>>5), ci=ciq*16+8*((lane>>4)&1)+j.
// C/D: col=lane&15 (co), row=(lane>>4)*4+reg (pix).
// NOTE launch_bounds (512,1): LDS (143KB) caps us at 1 block/CU regardless;
// (512,2) capped VGPR at 128 -> ~1.7KB/thread scratch spill -> 228MB HBM writes.
__global__ __launch_bounds__(512,1) void dcn_layer(
    const float* __restrict__ xin, const ushort* __restrict__ owPk,
    const float* __restrict__ ob, const ushort* __restrict__ dwPk,
    float* __restrict__ y, float* __restrict__ statsL)
{
    __shared__ __align__(16) char smem[143360];
    ushort* xt  = (ushort*)smem;                 // 960 spatial * 128B = 122880 B
    float* offl = (float*)(smem + 122880);       // [256][20] = 20480 B

    const int t = threadIdx.x, lane = t&63, w = t>>6;
    const int l15 = lane&15, lg = lane>>4;
    const int cih = lg&1, koff = lane>>5;
    const int bid = blockIdx.x;
    // XCD-aware bijective decode: xcd=bid&7 owns half an image (1MB < 4MB L2)
    const int xcd = bid&7, idx = bid>>3;
    const int b = xcd>>1, vh = xcd&1;
    const int ht = vh*8 + (idx>>2), wt = idx&3;
    const int w0 = wt*32, h0 = ht*8;
    const int row = h0 + w;
    const int RLO = h0-6, CLO = w0-8;

    // ================= stage full 64-ci halo tile (once) =================
#pragma unroll 1
    for (int i=0;i<30;i++){
        int d = i*512 + t;                 // 0..15359 : (cq 0..15) x (spatial 0..959)
        int cq = d/960, spatial = d - cq*960;
        int rowt = spatial/48, colt = spatial - rowt*48;
        int gy = RLO+rowt, gx = CLO+colt;
        bool ok = ((unsigned)gy<128u) && ((unsigned)gx<128u);
        const float* gp = xin + (((b<<6)+(cq<<2))<<14) + (gy<<7) + gx;
        short4v pk;
#pragma unroll
        for (int e=0;e<4;e++){
            float v = ok ? gp[e<<14] : 0.f;
            pk[e] = (short)f2bf(v);
        }
        int byt = spatial*128 + (((cq>>1)^(spatial&7))<<4) + ((cq&1)<<3);
        *(short4v*)(smem + byt) = pk;
    }
    __syncthreads();

    // ================= pass 1: offset conv via MFMA (A from LDS) =================
    f32x4 oacc[2][2];
#pragma unroll
    for (int p=0;p<2;p++)
#pragma unroll
        for (int q=0;q<2;q++) oacc[p][q] = (f32x4){0.f,0.f,0.f,0.f};

#pragma unroll 1
    for (int ciq=0; ciq<4; ++ciq) {
#pragma unroll
        for (int kkp=0; kkp<5; ++kkp) {
            const int kkA = 2*kkp, kkB = (2*kkp+1>8)?8:(2*kkp+1);
            int kh = koff ? KHt[kkB] : KHt[kkA];
            int kw = koff ? KWt[kkB] : KWt[kkA];
            short8v afr[2];
#pragma unroll
            for (int p=0;p<2;p++){
                int colt = p*16 + l15 + kw + 7;     // (w0+p*16+l15+kw-1) - CLO
                int rowt = w + 5 + kh;              // (row+kh-1) - RLO
                int sp = rowt*48 + colt;
                int byt = sp*128 + ((((ciq<<1)|cih) ^ (sp&7))<<4);
                afr[p] = *(const short8v*)(smem + byt);
            }
            const ushort* wop = owPk + ciq*5120 + kkp*1024 + koff*512 + cih*256;
#pragma unroll
            for (int q=0;q<2;q++){
                short4v b0 = *(const short4v*)(wop +       (q*16+l15)*4);
                short4v b1 = *(const short4v*)(wop + 128 + (q*16+l15)*4);
                short8v bb = __builtin_shufflevector(b0,b1,0,1,2,3,4,5,6,7);
#pragma unroll
                for (int p=0;p<2;p++)
                    oacc[p][q] = __builtin_amdgcn_mfma_f32_16x16x32_bf16(afr[p], bb, oacc[p][q], 0,0,0);
            }
        }
    }

    // redistribute offsets: offl[pix 256][20]; only o<18 (stride-20 overflow guard)
    float biasq[2];
#pragma unroll
    for (int q=0;q<2;q++){ int o = q*16+l15; biasq[q] = (o<18)? ob[o] : 0.f; }
#pragma unroll
    for (int p=0;p<2;p++)
#pragma unroll
        for (int q=0;q<2;q++){
            int o = q*16+l15;
            if (o < 18) {
#pragma unroll
                for (int r=0;r<4;r++){
                    int pix = w*32 + p*16 + lg*4 + r;
                    offl[pix*20 + o] = oacc[p][q][r] + biasq[q];
                }
            }
        }
    __syncthreads();
    float ofv[36];
#pragma unroll
    for (int p=0;p<2;p++){
        int pix = w*32 + p*16 + l15;
#pragma unroll
        for (int o=0;o<18;o++) ofv[p*18+o] = offl[pix*20 + o];
    }

    // ================= pass 2: deformable conv via MFMA (no restage, no syncs) =================
    f32x4 acc[2][4];
#pragma unroll
    for (int p=0;p<2;p++)
#pragma unroll
        for (int q=0;q<4;q++) acc[p][q] = (f32x4){0.f,0.f,0.f,0.f};

#pragma unroll 1
    for (int ciq=0; ciq<4; ++ciq) {
#pragma unroll
        for (int kkp=0; kkp<5; ++kkp) {
            const int kkA = 2*kkp, kkB = (2*kkp+1>8)?8:(2*kkp+1);
            int kh = koff ? KHt[kkB] : KHt[kkA];
            int kw = koff ? KWt[kkB] : KWt[kkA];
            short8v afr[2];
#pragma unroll
            for (int p=0;p<2;p++){
                float dy = koff ? ofv[p*18+2*kkB]   : ofv[p*18+2*kkA];
                float dx = koff ? ofv[p*18+2*kkB+1] : ofv[p*18+2*kkA+1];
                float py = (float)(row + kh - 1) + dy;
                float px = (float)(w0 + p*16 + l15 + kw - 1) + dx;
                float fy = floorf(py), fx = floorf(px);
                float ly = py - fy, lx = px - fx;
                int y0 = (int)fy, x0 = (int)fx;
                int y1 = y0+1, x1 = x0+1;
                bool vy0 = ((unsigned)y0<128u), vy1 = ((unsigned)y1<128u);
                bool vx0 = ((unsigned)x0<128u), vx1 = ((unsigned)x1<128u);
                int y0c = min(max(y0,0),127), y1c = min(max(y1,0),127);
                int x0c = min(max(x0,0),127), x1c = min(max(x1,0),127);
                int r0 = y0c-RLO, r1 = y1c-RLO, c0 = x0c-CLO, c1 = x1c-CLO;
                bool ty0 = ((unsigned)r0<20u), ty1 = ((unsigned)r1<20u);
                bool tx0 = ((unsigned)c0<48u), tx1 = ((unsigned)c1<48u);
                float g00 = (vy0&&vx0) ? (1.f-ly)*(1.f-lx) : 0.f;
                float g01 = (vy0&&vx1) ? (1.f-ly)*lx       : 0.f;
                float g10 = (vy1&&vx0) ? ly*(1.f-lx)       : 0.f;
                float g11 = (vy1&&vx1) ? ly*lx             : 0.f;
                float f00 = (ty0&&tx0) ? g00 : 0.f;
                float f01 = (ty0&&tx1) ? g01 : 0.f;
                float f10 = (ty1&&tx0) ? g10 : 0.f;
                float f11 = (ty1&&tx1) ? g11 : 0.f;
                int rc0 = min(max(r0,0),19), rc1 = min(max(r1,0),19);
                int cc0 = min(max(c0,0),47), cc1 = min(max(c1,0),47);
                int s00 = rc0*48+cc0, s01 = rc0*48+cc1, s10 = rc1*48+cc0, s11 = rc1*48+cc1;
                int slot = (ciq<<1)|cih;
                short8v q00 = *(const short8v*)(smem + s00*128 + ((slot^(s00&7))<<4));
                short8v q01 = *(const short8v*)(smem + s01*128 + ((slot^(s01&7))<<4));
                short8v q10 = *(const short8v*)(smem + s10*128 + ((slot^(s10&7))<<4));
                short8v q11 = *(const short8v*)(smem + s11*128 + ((slot^(s11&7))<<4));
                float sv[8];
#pragma unroll
                for (int j=0;j<8;j++)
                    sv[j] = f00*bf2f((ushort)q00[j]) + f01*bf2f((ushort)q01[j])
                          + f10*bf2f((ushort)q10[j]) + f11*bf2f((ushort)q11[j]);
                // rare fallback: in-image but out-of-tile corners read global fp32
                float r00 = g00-f00, r01 = g01-f01, r10 = g10-f10, r11 = g11-f11;
                if (r00+r01+r10+r11 > 0.f) {
                    const float* xg = xin + (((b<<6) + ciq*16 + cih*8)<<14);
                    int a00 = (y0c<<7)+x0c, a01 = (y0c<<7)+x1c;
                    int a10 = (y1c<<7)+x0c, a11 = (y1c<<7)+x1c;
#pragma unroll
                    for (int j=0;j<8;j++){
                        int o = j<<14;
                        sv[j] += r00*xg[a00+o] + r01*xg[a01+o]
                               + r10*xg[a10+o] + r11*xg[a11+o];
                    }
                }
#pragma unroll
                for (int j=0;j<8;j++) afr[p][j] = (short)f2bf(sv[j]);
            }
            const ushort* wp = dwPk + ciq*10240 + kkp*2048 + koff*1024 + cih*512;
#pragma unroll
            for (int q=0;q<4;q++){
                short4v b0 = *(const short4v*)(wp +       (q*16+l15)*4);
                short4v b1 = *(const short4v*)(wp + 256 + (q*16+l15)*4);
                short8v bb = __builtin_shufflevector(b0,b1,0,1,2,3,4,5,6,7);
                acc[0][q] = __builtin_amdgcn_mfma_f32_16x16x32_bf16(afr[0], bb, acc[0][q], 0,0,0);
                acc[1][q] = __builtin_amdgcn_mfma_f32_16x16x32_bf16(afr[1], bb, acc[1][q], 0,0,0);
            }
        }
    }

    // ================= epilogue: LDS transpose, store, stats (fully unrolled: no spill) =================
    float* yt  = (float*)smem;               // [32 co][260] = 33280 B (overlays xt)
    float* red = (float*)(smem + 33280);     // 1024 f32
#pragma unroll
    for (int half=0; half<2; ++half){
        __syncthreads();   // iter0: pass-2 xt reads done; iter1: prev stats reads done
#pragma unroll
        for (int p=0;p<2;p++)
#pragma unroll
            for (int qq=0;qq<2;qq++)
                *(f32x4*)(yt + (qq*16+l15)*260 + w*32 + p*16 + lg*4) = acc[p][half*2+qq];
        __syncthreads();
#pragma unroll
        for (int i=0;i<4;i++){
            int f4 = i*512 + t;
            int co = f4>>6, px4 = (f4&63)<<2;
            f32x4 v = *(const f32x4*)(yt + co*260 + px4);
            *(f32x4*)(y + (((b<<6) + half*32 + co)<<14) + (h0 + (px4>>5))*128 + w0 + (px4&31)) = v;
        }
        {
            float s=0.f, s2=0.f;
            int co = t&31, seg = t>>5;
            const float* bp = yt + co*260 + seg*16;
#pragma unroll
            for (int qd=0;qd<16;qd++){ float v = bp[qd]; s += v; s2 += v*v; }
            red[seg*32+co] = s; red[512 + seg*32+co] = s2;
        }
        __syncthreads();
        if (t < 64){
            int vv = t>>5, cc = t&31;
            float a = 0.f;
#pragma unroll
            for (int g=0;g<16;g++) a += red[vv*512 + g*32 + cc];
            atomicAdd(statsL + (bid&7)*128 + vv*64 + half*32 + cc, a);
        }
    }
}

// ---------------- normalize + ReLU + epilogue, stats finalized inline ----------------
// mode 0: out = relu(.)   mode 1: out = relu(.) + addsrc   mode 2: out += relu(.)
__global__ __launch_bounds__(256) void norm2(
    const float* __restrict__ yv, const float* __restrict__ statsL,
    const float* __restrict__ gamma, const float* __restrict__ beta,
    const float* __restrict__ addsrc, float* out, int mode)
{
    const int i4 = blockIdx.x*256 + threadIdx.x;
    const int ch = (i4 >> 12) & 63;
    float sum=0.f, ssq=0.f;
#pragma unroll
    for (int s=0;s<8;s++){ sum += statsL[s*128+ch]; ssq += statsL[s*128+64+ch]; }
    float mean = sum*(1.f/65536.f);
    float var  = ssq*(1.f/65536.f) - mean*mean;
    float inv  = rsqrtf(var + 1e-5f);
    float sc = gamma[ch]*inv, sh = beta[ch] - mean*sc;
    float4 v = *(const float4*)&yv[i4*4];
    float4 rr;
    rr.x = fmaxf(v.x*sc+sh, 0.f);
    rr.y = fmaxf(v.y*sc+sh, 0.f);
    rr.z = fmaxf(v.z*sc+sh, 0.f);
    rr.w = fmaxf(v.w*sc+sh, 0.f);
    if (mode == 1) {
        float4 a = *(const float4*)&addsrc[i4*4];
        rr.x+=a.x; rr.y+=a.y; rr.z+=a.z; rr.w+=a.w;
    } else if (mode == 2) {
        float4 o = *(const float4*)&out[i4*4];
        rr.x+=o.x; rr.y+=o.y; rr.z+=o.z; rr.w+=o.w;
    }
    *(float4*)&out[i4*4] = rr;
}

// ---------------- host orchestration ----------------
extern "C" void kernel_launch(void* const* d_in, const int* in_sizes, int n_in,
                              void* d_out, int out_size, void* d_ws, size_t ws_size,
                              hipStream_t stream)
{
    const float* x  = (const float*)d_in[0];
    const float* ow = (const float*)d_in[1];
    const float* ob = (const float*)d_in[2];
    const float* dw = (const float*)d_in[3];
    const float* g  = (const float*)d_in[4];
    const float* be = (const float*)d_in[5];
    float* out = (float*)d_out;

    float*  yb     = (float*)d_ws;
    float*  P      = yb + NTOT;
    float*  Q      = P + NTOT;
    float*  statsG = Q + NTOT;               // 7*1024 f32
    ushort* dwPk   = (ushort*)(statsG + 7*1024);
    ushort* owPk   = dwPk + 286720;

    pack_w<<<1120, 256, 0, stream>>>(dw, ow, dwPk, owPk, statsG);

    auto L = [&](int l, const float* in, float* dst, int mode, const float* adds){
        dcn_layer<<<256, 512, 0, stream>>>(in, owPk + l*20480, ob + l*18,
                                           dwPk + l*40960, yb, statsG + l*1024);
        norm2<<<4096, 256, 0, stream>>>(yb, statsG + l*1024, g + l*64, be + l*64,
                                        adds, dst, mode);
    };

    L(0, x, P,   0, nullptr);   // P = L0(x)
    L(1, P, P,   0, nullptr);   // P = L1(P)            (out_1)
    L(4, x, Q,   1, P);         // Q = L4(x) + P        (out_sum_1)
    L(2, Q, P,   0, nullptr);   // P = L2(Q)
    L(3, P, out, 0, nullptr);   // out = L3(P)
    L(5, Q, out, 2, nullptr);   // out += L5(Q)
    L(6, Q, out, 2, nullptr);   // out += L6(Q)
}

// Round 8
// 425.714 us; speedup vs baseline: 9.4283x; 1.3954x over previous
//
#include <hip/hip_runtime.h>

#define NTOT 4194304
typedef __attribute__((ext_vector_type(4)))  short short4v;
typedef __attribute__((ext_vector_type(8)))  short short8v;
typedef __attribute__((ext_vector_type(4)))  float f32x4;

__device__ __forceinline__ ushort f2bf(float f){
    unsigned u = __float_as_uint(f);
    return (ushort)((u + 0x7FFFu + ((u>>16)&1u)) >> 16);
}
__device__ __forceinline__ float bf2f(ushort u){
    return __uint_as_float(((unsigned)u)<<16);
}

// ---------------- weight pack: per-lane MFMA B-fragment order, bf16 ----------------
// dwPk[l][ciq4][kkp5][koff2][cih2][jg2][co64][j4]
// owPk[l][ciq4][kkp5][koff2][cih2][jg2][co32][j4]
__global__ __launch_bounds__(256) void pack_w(
    const float* __restrict__ dw, const float* __restrict__ ow,
    ushort* __restrict__ dwPk, ushort* __restrict__ owPk,
    float* __restrict__ statsG)
{
    int i = blockIdx.x*256 + threadIdx.x;
    if (i < 286720) {
        int j = i&3, co = (i>>2)&63, jg=(i>>8)&1, cih=(i>>9)&1, koff=(i>>10)&1;
        int r = i>>11; int kkp = r%5; int r2 = r/5; int ciq = r2&3; int l = r2>>2;
        int kk = kkp*2+koff, ci = ciq*16 + cih*8 + jg*4 + j;
        float v = (kk<9)? dw[((l*64+co)*64+ci)*9+kk] : 0.f;
        dwPk[i] = f2bf(v);
    }
    if (i < 143360) {
        int j = i&3, co = (i>>2)&31, jg=(i>>7)&1, cih=(i>>8)&1, koff=(i>>9)&1;
        int r = i>>10; int kkp = r%5; int r2 = r/5; int ciq = r2&3; int l = r2>>2;
        int kk = kkp*2+koff, ci = ciq*16 + cih*8 + jg*4 + j;
        float v = (kk<9 && co<18)? ow[((l*18+co)*64+ci)*9+kk] : 0.f;
        owPk[i] = f2bf(v);
    }
    if (i < 7*1024) statsG[i] = 0.f;   // zero stats accumulators (capture-safe)
}

// kh/kw tables; index 9 clamps to kk=8 (ghost K-slots carry zero weights)
__constant__ int KHt[10] = {0,0,0,1,1,1,2,2,2,2};
__constant__ int KWt[10] = {0,1,2,0,1,2,0,1,2,2};

// ---------------- fused offset-conv + deformable conv, single LDS stage ----------------
// Block: 512 thr = 8 waves; tile 8 rows x 32 cols. Grid 256, XCD-bijective decode.
// LDS xt: [spatial 20x48][ci 64] bf16, 16B slot index XOR-swizzled by (spatial&7).
// A-frag lane: pixel = p*16+(lane&15); k-slot: kk=2kkp+(lane>>5), ci=ciq*16+8*((lane>>4)&1)+j.
// C/D: col=lane&15 (co), row=(lane>>4)*4+reg (pix).
// Occupancy: LDS 143KB -> 1 block/CU = 2 waves/EU. Explicit waves_per_eu(2,2)
// gives the allocator the full 256-VGPR budget (launch_bounds capped us at 128
// -> 212MB/dispatch scratch spill, rounds 6-7). Offsets live in LDS (offl),
// not a 36-reg array; kkp loops are unroll-1 to bound peak pressure.
__global__ __attribute__((amdgpu_flat_work_group_size(512,512), amdgpu_waves_per_eu(2,2)))
void dcn_layer(
    const float* __restrict__ xin, const ushort* __restrict__ owPk,
    const float* __restrict__ ob, const ushort* __restrict__ dwPk,
    float* __restrict__ y, float* __restrict__ statsL)
{
    __shared__ __align__(16) char smem[143360];
    ushort* xt  = (ushort*)smem;                 // 960 spatial * 128B = 122880 B
    float* offl = (float*)(smem + 122880);       // [256][20] = 20480 B

    const int t = threadIdx.x, lane = t&63, w = t>>6;
    const int l15 = lane&15, lg = lane>>4;
    const int cih = lg&1, koff = lane>>5;
    const int bid = blockIdx.x;
    // XCD-aware bijective decode: xcd=bid&7 owns half an image (1MB < 4MB L2)
    const int xcd = bid&7, idx = bid>>3;
    const int b = xcd>>1, vh = xcd&1;
    const int ht = vh*8 + (idx>>2), wt = idx&3;
    const int w0 = wt*32, h0 = ht*8;
    const int row = h0 + w;
    const int RLO = h0-6, CLO = w0-8;

    // ================= stage full 64-ci halo tile (once) =================
#pragma unroll 1
    for (int i=0;i<30;i++){
        int d = i*512 + t;                 // 0..15359 : (cq 0..15) x (spatial 0..959)
        int cq = d/960, spatial = d - cq*960;
        int rowt = spatial/48, colt = spatial - rowt*48;
        int gy = RLO+rowt, gx = CLO+colt;
        bool ok = ((unsigned)gy<128u) && ((unsigned)gx<128u);
        const float* gp = xin + (((b<<6)+(cq<<2))<<14) + (gy<<7) + gx;
        short4v pk;
#pragma unroll
        for (int e=0;e<4;e++){
            float v = ok ? gp[e<<14] : 0.f;
            pk[e] = (short)f2bf(v);
        }
        int byt = spatial*128 + (((cq>>1)^(spatial&7))<<4) + ((cq&1)<<3);
        *(short4v*)(smem + byt) = pk;
    }
    __syncthreads();

    // ================= pass 1: offset conv via MFMA (A from LDS) =================
    f32x4 oacc[2][2];
#pragma unroll
    for (int p=0;p<2;p++)
#pragma unroll
        for (int q=0;q<2;q++) oacc[p][q] = (f32x4){0.f,0.f,0.f,0.f};

#pragma unroll 1
    for (int ciq=0; ciq<4; ++ciq) {
#pragma unroll 1
        for (int kkp=0; kkp<5; ++kkp) {
            int kkA = 2*kkp;
            int kkB = (kkA+1>8)?8:(kkA+1);
            int kh = koff ? KHt[kkB] : KHt[kkA];
            int kw = koff ? KWt[kkB] : KWt[kkA];
            short8v afr[2];
#pragma unroll
            for (int p=0;p<2;p++){
                int colt = p*16 + l15 + kw + 7;     // (w0+p*16+l15+kw-1) - CLO
                int rowt = w + 5 + kh;              // (row+kh-1) - RLO
                int sp = rowt*48 + colt;
                int byt = sp*128 + ((((ciq<<1)|cih) ^ (sp&7))<<4);
                afr[p] = *(const short8v*)(smem + byt);
            }
            const ushort* wop = owPk + ciq*5120 + kkp*1024 + koff*512 + cih*256;
#pragma unroll
            for (int q=0;q<2;q++){
                short4v b0 = *(const short4v*)(wop +       (q*16+l15)*4);
                short4v b1 = *(const short4v*)(wop + 128 + (q*16+l15)*4);
                short8v bb = __builtin_shufflevector(b0,b1,0,1,2,3,4,5,6,7);
#pragma unroll
                for (int p=0;p<2;p++)
                    oacc[p][q] = __builtin_amdgcn_mfma_f32_16x16x32_bf16(afr[p], bb, oacc[p][q], 0,0,0);
            }
        }
    }

    // redistribute offsets: offl[pix 256][20]; only o<18 (stride-20 overflow guard)
    float biasq[2];
#pragma unroll
    for (int q=0;q<2;q++){ int o = q*16+l15; biasq[q] = (o<18)? ob[o] : 0.f; }
#pragma unroll
    for (int p=0;p<2;p++)
#pragma unroll
        for (int q=0;q<2;q++){
            int o = q*16+l15;
            if (o < 18) {
#pragma unroll
                for (int r=0;r<4;r++){
                    int pix = w*32 + p*16 + lg*4 + r;
                    offl[pix*20 + o] = oacc[p][q][r] + biasq[q];
                }
            }
        }
    __syncthreads();

    // ================= pass 2: deformable conv via MFMA (offsets read from LDS) =================
    f32x4 acc[2][4];
#pragma unroll
    for (int p=0;p<2;p++)
#pragma unroll
        for (int q=0;q<4;q++) acc[p][q] = (f32x4){0.f,0.f,0.f,0.f};

#pragma unroll 1
    for (int ciq=0; ciq<4; ++ciq) {
#pragma unroll 1
        for (int kkp=0; kkp<5; ++kkp) {
            int kkA = 2*kkp;
            int kkB = (kkA+1>8)?8:(kkA+1);
            int kh = koff ? KHt[kkB] : KHt[kkA];
            int kw = koff ? KWt[kkB] : KWt[kkA];
            int kkX = koff ? kkB : kkA;
            short8v afr[2];
#pragma unroll
            for (int p=0;p<2;p++){
                int pix = w*32 + p*16 + l15;
                float2 od = *(const float2*)(offl + pix*20 + 2*kkX);
                float dy = od.x, dx = od.y;
                float py = (float)(row + kh - 1) + dy;
                float px = (float)(w0 + p*16 + l15 + kw - 1) + dx;
                float fy = floorf(py), fx = floorf(px);
                float ly = py - fy, lx = px - fx;
                int y0 = (int)fy, x0 = (int)fx;
                int y1 = y0+1, x1 = x0+1;
                bool vy0 = ((unsigned)y0<128u), vy1 = ((unsigned)y1<128u);
                bool vx0 = ((unsigned)x0<128u), vx1 = ((unsigned)x1<128u);
                int y0c = min(max(y0,0),127), y1c = min(max(y1,0),127);
                int x0c = min(max(x0,0),127), x1c = min(max(x1,0),127);
                int r0 = y0c-RLO, r1 = y1c-RLO, c0 = x0c-CLO, c1 = x1c-CLO;
                bool ty0 = ((unsigned)r0<20u), ty1 = ((unsigned)r1<20u);
                bool tx0 = ((unsigned)c0<48u), tx1 = ((unsigned)c1<48u);
                float g00 = (vy0&&vx0) ? (1.f-ly)*(1.f-lx) : 0.f;
                float g01 = (vy0&&vx1) ? (1.f-ly)*lx       : 0.f;
                float g10 = (vy1&&vx0) ? ly*(1.f-lx)       : 0.f;
                float g11 = (vy1&&vx1) ? ly*lx             : 0.f;
                float f00 = (ty0&&tx0) ? g00 : 0.f;
                float f01 = (ty0&&tx1) ? g01 : 0.f;
                float f10 = (ty1&&tx0) ? g10 : 0.f;
                float f11 = (ty1&&tx1) ? g11 : 0.f;
                int rc0 = min(max(r0,0),19), rc1 = min(max(r1,0),19);
                int cc0 = min(max(c0,0),47), cc1 = min(max(c1,0),47);
                int s00 = rc0*48+cc0, s01 = rc0*48+cc1, s10 = rc1*48+cc0, s11 = rc1*48+cc1;
                int slot = (ciq<<1)|cih;
                short8v q00 = *(const short8v*)(smem + s00*128 + ((slot^(s00&7))<<4));
                short8v q01 = *(const short8v*)(smem + s01*128 + ((slot^(s01&7))<<4));
                short8v q10 = *(const short8v*)(smem + s10*128 + ((slot^(s10&7))<<4));
                short8v q11 = *(const short8v*)(smem + s11*128 + ((slot^(s11&7))<<4));
                float sv[8];
#pragma unroll
                for (int j=0;j<8;j++)
                    sv[j] = f00*bf2f((ushort)q00[j]) + f01*bf2f((ushort)q01[j])
                          + f10*bf2f((ushort)q10[j]) + f11*bf2f((ushort)q11[j]);
                // rare fallback: in-image but out-of-tile corners read global fp32
                float r00 = g00-f00, r01 = g01-f01, r10 = g10-f10, r11 = g11-f11;
                if (r00+r01+r10+r11 > 0.f) {
                    const float* xg = xin + (((b<<6) + ciq*16 + cih*8)<<14);
                    int a00 = (y0c<<7)+x0c, a01 = (y0c<<7)+x1c;
                    int a10 = (y1c<<7)+x0c, a11 = (y1c<<7)+x1c;
#pragma unroll
                    for (int j=0;j<8;j++){
                        int o = j<<14;
                        sv[j] += r00*xg[a00+o] + r01*xg[a01+o]
                               + r10*xg[a10+o] + r11*xg[a11+o];
                    }
                }
#pragma unroll
                for (int j=0;j<8;j++) afr[p][j] = (short)f2bf(sv[j]);
            }
            const ushort* wp = dwPk + ciq*10240 + kkp*2048 + koff*1024 + cih*512;
#pragma unroll
            for (int q=0;q<4;q++){
                short4v b0 = *(const short4v*)(wp +       (q*16+l15)*4);
                short4v b1 = *(const short4v*)(wp + 256 + (q*16+l15)*4);
                short8v bb = __builtin_shufflevector(b0,b1,0,1,2,3,4,5,6,7);
                acc[0][q] = __builtin_amdgcn_mfma_f32_16x16x32_bf16(afr[0], bb, acc[0][q], 0,0,0);
                acc[1][q] = __builtin_amdgcn_mfma_f32_16x16x32_bf16(afr[1], bb, acc[1][q], 0,0,0);
            }
        }
    }

    // ================= epilogue: LDS transpose, store, stats (fully unrolled: no spill) =================
    float* yt  = (float*)smem;               // [32 co][260] = 33280 B (overlays xt)
    float* red = (float*)(smem + 33280);     // 1024 f32
#pragma unroll
    for (int half=0; half<2; ++half){
        __syncthreads();   // iter0: pass-2 xt reads done; iter1: prev stats reads done
#pragma unroll
        for (int p=0;p<2;p++)
#pragma unroll
            for (int qq=0;qq<2;qq++)
                *(f32x4*)(yt + (qq*16+l15)*260 + w*32 + p*16 + lg*4) = acc[p][half*2+qq];
        __syncthreads();
#pragma unroll
        for (int i=0;i<4;i++){
            int f4 = i*512 + t;
            int co = f4>>6, px4 = (f4&63)<<2;
            f32x4 v = *(const f32x4*)(yt + co*260 + px4);
            *(f32x4*)(y + (((b<<6) + half*32 + co)<<14) + (h0 + (px4>>5))*128 + w0 + (px4&31)) = v;
        }
        {
            float s=0.f, s2=0.f;
            int co = t&31, seg = t>>5;
            const float* bp = yt + co*260 + seg*16;
#pragma unroll
            for (int qd=0;qd<16;qd++){ float v = bp[qd]; s += v; s2 += v*v; }
            red[seg*32+co] = s; red[512 + seg*32+co] = s2;
        }
        __syncthreads();
        if (t < 64){
            int vv = t>>5, cc = t&31;
            float a = 0.f;
#pragma unroll
            for (int g=0;g<16;g++) a += red[vv*512 + g*32 + cc];
            atomicAdd(statsL + (bid&7)*128 + vv*64 + half*32 + cc, a);
        }
    }
}

// ---------------- normalize + ReLU + epilogue, stats finalized inline ----------------
// mode 0: out = relu(.)   mode 1: out = relu(.) + addsrc   mode 2: out += relu(.)
__global__ __launch_bounds__(256) void norm2(
    const float* __restrict__ yv, const float* __restrict__ statsL,
    const float* __restrict__ gamma, const float* __restrict__ beta,
    const float* __restrict__ addsrc, float* out, int mode)
{
    const int i4 = blockIdx.x*256 + threadIdx.x;
    const int ch = (i4 >> 12) & 63;
    float sum=0.f, ssq=0.f;
#pragma unroll
    for (int s=0;s<8;s++){ sum += statsL[s*128+ch]; ssq += statsL[s*128+64+ch]; }
    float mean = sum*(1.f/65536.f);
    float var  = ssq*(1.f/65536.f) - mean*mean;
    float inv  = rsqrtf(var + 1e-5f);
    float sc = gamma[ch]*inv, sh = beta[ch] - mean*sc;
    float4 v = *(const float4*)&yv[i4*4];
    float4 rr;
    rr.x = fmaxf(v.x*sc+sh, 0.f);
    rr.y = fmaxf(v.y*sc+sh, 0.f);
    rr.z = fmaxf(v.z*sc+sh, 0.f);
    rr.w = fmaxf(v.w*sc+sh, 0.f);
    if (mode == 1) {
        float4 a = *(const float4*)&addsrc[i4*4];
        rr.x+=a.x; rr.y+=a.y; rr.z+=a.z; rr.w+=a.w;
    } else if (mode == 2) {
        float4 o = *(const float4*)&out[i4*4];
        rr.x+=o.x; rr.y+=o.y; rr.z+=o.z; rr.w+=o.w;
    }
    *(float4*)&out[i4*4] = rr;
}

// ---------------- host orchestration ----------------
extern "C" void kernel_launch(void* const* d_in, const int* in_sizes, int n_in,
                              void* d_out, int out_size, void* d_ws, size_t ws_size,
                              hipStream_t stream)
{
    const float* x  = (const float*)d_in[0];
    const float* ow = (const float*)d_in[1];
    const float* ob = (const float*)d_in[2];
    const float* dw = (const float*)d_in[3];
    const float* g  = (const float*)d_in[4];
    const float* be = (const float*)d_in[5];
    float* out = (float*)d_out;

    float*  yb     = (float*)d_ws;
    float*  P      = yb + NTOT;
    float*  Q      = P + NTOT;
    float*  statsG = Q + NTOT;               // 7*1024 f32
    ushort* dwPk   = (ushort*)(statsG + 7*1024);
    ushort* owPk   = dwPk + 286720;

    pack_w<<<1120, 256, 0, stream>>>(dw, ow, dwPk, owPk, statsG);

    auto L = [&](int l, const float* in, float* dst, int mode, const float* adds){
        dcn_layer<<<256, 512, 0, stream>>>(in, owPk + l*20480, ob + l*18,
                                           dwPk + l*40960, yb, statsG + l*1024);
        norm2<<<4096, 256, 0, stream>>>(yb, statsG + l*1024, g + l*64, be + l*64,
                                        adds, dst, mode);
    };

    L(0, x, P,   0, nullptr);   // P = L0(x)
    L(1, P, P,   0, nullptr);   // P = L1(P)            (out_1)
    L(4, x, Q,   1, P);         // Q = L4(x) + P        (out_sum_1)
    L(2, Q, P,   0, nullptr);   // P = L2(Q)
    L(3, P, out, 0, nullptr);   // out = L3(P)
    L(5, Q, out, 2, nullptr);   // out += L5(Q)
    L(6, Q, out, 2, nullptr);   // out += L6(Q)
}